// Round 8
// baseline (381.332 us; speedup 1.0000x reference)
//
#include <hip/hip_runtime.h>
#include <math.h>

#define N_NODES 50000
#define N_EDGES 800000
#define FDIM 512                 // HEADS*OUT_CH
#define NEG_SLOPE 0.2f
#define CAP 64                   // bucket slots per node; in-deg ~Poisson(16), max~40

#define GEMM_BLKS 782            // ceil(50000/64)
#define FILL_BLKS 3125           // ceil(800000/256) — 1 edge/thread

typedef _Float16 v2h __attribute__((ext_vector_type(2)));
typedef _Float16 v8h __attribute__((ext_vector_type(8)));
typedef float f32x4 __attribute__((ext_vector_type(4)));

#if __has_builtin(__builtin_amdgcn_exp2f)
#define EXP2(x) __builtin_amdgcn_exp2f(x)
#else
#define EXP2(x) __expf((x) * 0.69314718056f)
#endif
#define LOG2E 1.44269504089f

__device__ __forceinline__ v2h pack_h2(float a, float b) {
    v2h r; r.x = (_Float16)a; r.y = (_Float16)b; return r;
}

// ---------------------------------------------------------------------------
// Fused preproc: blocks [0,GEMM_BLKS) compute x_l -> fp16 table; blocks
// [GEMM_BLKS, ...) scatter edges into per-dst buckets (proven config).
__global__ __launch_bounds__(256) void preproc_kernel(const float* __restrict__ feat,
                                                      const float* __restrict__ Wl,
                                                      unsigned int* __restrict__ xlb,
                                                      const int* __restrict__ ei,
                                                      int* __restrict__ deg,
                                                      int* __restrict__ bucket) {
    int t = threadIdx.x;
    if (blockIdx.x >= GEMM_BLKS) {
        // ---- fill_bucket part ----
        bool is64 = true;
#pragma unroll
        for (int i = 0; i < 16; i++) is64 = is64 && (ei[2 * i + 1] == 0);
        int e = (blockIdx.x - GEMM_BLKS) * 256 + t;
        if (e < N_EDGES) {
            int src = is64 ? ei[2 * e] : ei[e];
            int dst = is64 ? ei[2 * (N_EDGES + e)] : ei[N_EDGES + e];
            int pos = atomicAdd(&deg[dst], 1);
            if (pos < CAP) bucket[dst * CAP + pos] = src;
        }
        return;
    }

    // ---- gemm_xl part: x_l = feat @ W_l, stored as packed fp16 pairs ----
    __shared__ float fsh[64 * 16];
    int node0 = blockIdx.x * 64;
    int nvalid = min(64, N_NODES - node0);

    float w0[16], w1[16];
#pragma unroll
    for (int k = 0; k < 16; k++) {
        float2 w = ((const float2*)(Wl + k * FDIM))[t];
        w0[k] = w.x; w1[k] = w.y;
    }
    if (t < nvalid * 4) {
        ((float4*)fsh)[t] = ((const float4*)(feat + (size_t)node0 * 16))[t];
    }
    __syncthreads();

    for (int n = 0; n < nvalid; n++) {
        const float4* fq = (const float4*)(fsh + n * 16);
        float4 q0 = fq[0], q1 = fq[1], q2 = fq[2], q3 = fq[3];
        float fr[16] = {q0.x, q0.y, q0.z, q0.w, q1.x, q1.y, q1.z, q1.w,
                        q2.x, q2.y, q2.z, q2.w, q3.x, q3.y, q3.z, q3.w};
        float a0 = 0.f, a1 = 0.f;
#pragma unroll
        for (int k = 0; k < 16; k++) {
            a0 = fmaf(fr[k], w0[k], a0);
            a1 = fmaf(fr[k], w1[k], a1);
        }
        v2h hv = pack_h2(a0, a1);
        xlb[(size_t)(node0 + n) * 256 + t] = __builtin_bit_cast(unsigned int, hv);
    }
}

// ---------------------------------------------------------------------------
// DPP rotate-add within each 16-lane row (one head): cheap all-reduce.
#define DPP_ROR_ADD(x, ctrl) \
    ((x) + __int_as_float(__builtin_amdgcn_update_dpp(0, __float_as_int(x), (ctrl), 0xF, 0xF, true)))

// Per-lane partial score over 8 fp16 channels; a2 is att*log2e in fp16.
__device__ __forceinline__ float score8(uint4 u, const v2h* __restrict__ xr2,
                                        const v2h* __restrict__ a2, v2h sl) {
    v2h x0 = __builtin_bit_cast(v2h, u.x);
    v2h x1 = __builtin_bit_cast(v2h, u.y);
    v2h x2 = __builtin_bit_cast(v2h, u.z);
    v2h x3 = __builtin_bit_cast(v2h, u.w);
#if __has_builtin(__builtin_amdgcn_fdot2)
    float ps = 0.f;
    v2h s;
    s = x0 + xr2[0]; s = __builtin_elementwise_max(s, s * sl);
    ps = __builtin_amdgcn_fdot2(s, a2[0], ps, false);
    s = x1 + xr2[1]; s = __builtin_elementwise_max(s, s * sl);
    ps = __builtin_amdgcn_fdot2(s, a2[1], ps, false);
    s = x2 + xr2[2]; s = __builtin_elementwise_max(s, s * sl);
    ps = __builtin_amdgcn_fdot2(s, a2[2], ps, false);
    s = x3 + xr2[3]; s = __builtin_elementwise_max(s, s * sl);
    ps = __builtin_amdgcn_fdot2(s, a2[3], ps, false);
    return ps;
#else
    v2h ps = {(_Float16)0.f, (_Float16)0.f};
    v2h s;
    s = x0 + xr2[0]; ps += __builtin_elementwise_max(s, s * sl) * a2[0];
    s = x1 + xr2[1]; ps += __builtin_elementwise_max(s, s * sl) * a2[1];
    s = x2 + xr2[2]; ps += __builtin_elementwise_max(s, s * sl) * a2[2];
    s = x3 + xr2[3]; ps += __builtin_elementwise_max(s, s * sl) * a2[3];
    return (float)ps.x + (float)ps.y;
#endif
}

// Gather one batch of 4 edges; invalid slots re-load the node's own row
// (harmless, L2-hot). 32-bit byte offsets (row = 1 KB, table 51 MB).
__device__ __forceinline__ void load_batch(const int* __restrict__ brow, int k, int dn,
                                           int node, const char* __restrict__ xlb_b,
                                           unsigned lane16, uint4* __restrict__ u) {
    int4 q = *(const int4*)(brow + k);
    unsigned o0 = ((unsigned)((k     < dn) ? q.x : node) << 10) + lane16;
    unsigned o1 = ((unsigned)((k + 1 < dn) ? q.y : node) << 10) + lane16;
    unsigned o2 = ((unsigned)((k + 2 < dn) ? q.z : node) << 10) + lane16;
    unsigned o3 = ((unsigned)((k + 3 < dn) ? q.w : node) << 10) + lane16;
    u[0] = *(const uint4*)(xlb_b + o0);
    u[1] = *(const uint4*)(xlb_b + o1);
    u[2] = *(const uint4*)(xlb_b + o2);
    u[3] = *(const uint4*)(xlb_b + o3);
}

// Single-path online-softmax update (exp2-space); r masks the tail batch.
__device__ __forceinline__ void process_batch(const uint4* __restrict__ u, int r,
                                              const v2h* __restrict__ xr2,
                                              const v2h* __restrict__ a2, v2h sl,
                                              float* __restrict__ acc,
                                              float& m, float& d) {
    float p0 = score8(u[0], xr2, a2, sl);
    float p1 = score8(u[1], xr2, a2, sl);
    float p2 = score8(u[2], xr2, a2, sl);
    float p3 = score8(u[3], xr2, a2, sl);

    // interleaved DPP all-reduce within each 16-lane head group
    p0 = DPP_ROR_ADD(p0, 0x128); p1 = DPP_ROR_ADD(p1, 0x128);
    p2 = DPP_ROR_ADD(p2, 0x128); p3 = DPP_ROR_ADD(p3, 0x128);
    p0 = DPP_ROR_ADD(p0, 0x124); p1 = DPP_ROR_ADD(p1, 0x124);
    p2 = DPP_ROR_ADD(p2, 0x124); p3 = DPP_ROR_ADD(p3, 0x124);
    p0 = DPP_ROR_ADD(p0, 0x122); p1 = DPP_ROR_ADD(p1, 0x122);
    p2 = DPP_ROR_ADD(p2, 0x122); p3 = DPP_ROR_ADD(p3, 0x122);
    p0 = DPP_ROR_ADD(p0, 0x121); p1 = DPP_ROR_ADD(p1, 0x121);
    p2 = DPP_ROR_ADD(p2, 0x121); p3 = DPP_ROR_ADD(p3, 0x121);

    if (r < 2) p1 = -INFINITY;
    if (r < 3) p2 = -INFINITY;
    if (r < 4) p3 = -INFINITY;

    float nm = fmaxf(fmaxf(fmaxf(m, p0), fmaxf(p1, p2)), p3);
    float sc = EXP2(m - nm);
    float w0 = EXP2(p0 - nm);
    float w1 = EXP2(p1 - nm);
    float w2 = EXP2(p2 - nm);
    float w3 = EXP2(p3 - nm);
    d = fmaf(d, sc, (w0 + w1) + (w2 + w3));

    v8h h0 = __builtin_bit_cast(v8h, u[0]);
    v8h h1 = __builtin_bit_cast(v8h, u[1]);
    v8h h2 = __builtin_bit_cast(v8h, u[2]);
    v8h h3 = __builtin_bit_cast(v8h, u[3]);
#pragma unroll
    for (int j = 0; j < 8; j++) {
        float v = acc[j] * sc;
        v = fmaf(w0, (float)h0[j], v);   // v_fma_mix-fusable
        v = fmaf(w1, (float)h1[j], v);
        v = fmaf(w2, (float)h2[j], v);
        v = fmaf(w3, (float)h3[j], v);
        acc[j] = v;
    }
    m = nm;
}

// One wave per destination node, 4 waves per block. Self-loop computed in
// registers (bit-exact vs the table row: same fmaf chain + pack), so the
// edge loop runs over dn real edges only — saves 51 MB of gather and one
// whole batch for the 25% of nodes with dn%4==0.
__global__ __launch_bounds__(256) void gat_aggregate_kernel(
        const float* __restrict__ feat, const float* __restrict__ Wl,
        const float* __restrict__ Wr,   const float* __restrict__ att,
        const float* __restrict__ bias, const char* __restrict__ xlb_b,
        const int* __restrict__ deg,    const int* __restrict__ bucket,
        float* __restrict__ out) {
    int t = threadIdx.x;
    int wave = t >> 6, lane = t & 63;
    int node = blockIdx.x * 4 + wave;    // grid*4 == N_NODES exactly
    int cbase = lane * 8;
    unsigned lane16 = (unsigned)lane << 4;

    // feat[node] broadcast
    float f[16];
    {
        const float4* fp = (const float4*)(feat + (size_t)node * 16);
        float4 f0 = fp[0], f1 = fp[1], f2 = fp[2], f3 = fp[3];
        f[0]=f0.x; f[1]=f0.y; f[2]=f0.z; f[3]=f0.w;
        f[4]=f1.x; f[5]=f1.y; f[6]=f1.z; f[7]=f1.w;
        f[8]=f2.x; f[9]=f2.y; f[10]=f2.z; f[11]=f2.w;
        f[12]=f3.x; f[13]=f3.y; f[14]=f3.z; f[15]=f3.w;
    }

    // x_r[node] for this lane's 8 channels, fp32 accumulate then pack to fp16
    float xr[8];
#pragma unroll
    for (int j = 0; j < 8; j++) xr[j] = 0.f;
#pragma unroll
    for (int k = 0; k < 16; k++) {
        float fk = f[k];
        float4 wa = *(const float4*)(Wr + k * FDIM + cbase);
        float4 wb = *(const float4*)(Wr + k * FDIM + cbase + 4);
        xr[0] = fmaf(fk, wa.x, xr[0]); xr[1] = fmaf(fk, wa.y, xr[1]);
        xr[2] = fmaf(fk, wa.z, xr[2]); xr[3] = fmaf(fk, wa.w, xr[3]);
        xr[4] = fmaf(fk, wb.x, xr[4]); xr[5] = fmaf(fk, wb.y, xr[5]);
        xr[6] = fmaf(fk, wb.z, xr[6]); xr[7] = fmaf(fk, wb.w, xr[7]);
    }
    v2h xr2[4];
    xr2[0] = pack_h2(xr[0], xr[1]);
    xr2[1] = pack_h2(xr[2], xr[3]);
    xr2[2] = pack_h2(xr[4], xr[5]);
    xr2[3] = pack_h2(xr[6], xr[7]);

    // att * log2e, packed fp16 (single rounding)
    v2h a2[4];
    {
        float4 a0 = *(const float4*)(att + cbase);
        float4 a1 = *(const float4*)(att + cbase + 4);
        a2[0] = pack_h2(a0.x * LOG2E, a0.y * LOG2E);
        a2[1] = pack_h2(a0.z * LOG2E, a0.w * LOG2E);
        a2[2] = pack_h2(a1.x * LOG2E, a1.y * LOG2E);
        a2[3] = pack_h2(a1.z * LOG2E, a1.w * LOG2E);
    }
    const v2h sl = {(_Float16)NEG_SLOPE, (_Float16)NEG_SLOPE};

    // x_l[node]: EXACT replica of the preproc arithmetic (ascending-k fmaf
    // chain, fp32, then pack_h2) -> bitwise identical to the table row.
    uint4 su;
    {
        float xl[8];
#pragma unroll
        for (int j = 0; j < 8; j++) xl[j] = 0.f;
#pragma unroll
        for (int k = 0; k < 16; k++) {
            float fk = f[k];
            float4 wa = *(const float4*)(Wl + k * FDIM + cbase);
            float4 wb = *(const float4*)(Wl + k * FDIM + cbase + 4);
            xl[0] = fmaf(fk, wa.x, xl[0]); xl[1] = fmaf(fk, wa.y, xl[1]);
            xl[2] = fmaf(fk, wa.z, xl[2]); xl[3] = fmaf(fk, wa.w, xl[3]);
            xl[4] = fmaf(fk, wb.x, xl[4]); xl[5] = fmaf(fk, wb.y, xl[5]);
            xl[6] = fmaf(fk, wb.z, xl[6]); xl[7] = fmaf(fk, wb.w, xl[7]);
        }
        su.x = __builtin_bit_cast(unsigned int, pack_h2(xl[0], xl[1]));
        su.y = __builtin_bit_cast(unsigned int, pack_h2(xl[2], xl[3]));
        su.z = __builtin_bit_cast(unsigned int, pack_h2(xl[4], xl[5]));
        su.w = __builtin_bit_cast(unsigned int, pack_h2(xl[6], xl[7]));
    }

    // Initialize online softmax with the self edge (weight exp2(0)=1).
    float p_self = score8(su, xr2, a2, sl);
    p_self = DPP_ROR_ADD(p_self, 0x128);
    p_self = DPP_ROR_ADD(p_self, 0x124);
    p_self = DPP_ROR_ADD(p_self, 0x122);
    p_self = DPP_ROR_ADD(p_self, 0x121);
    float m = p_self, d = 1.f;
    float acc[8];
    {
        v8h sh = __builtin_bit_cast(v8h, su);
#pragma unroll
        for (int j = 0; j < 8; j++) acc[j] = (float)sh[j];
    }

    int dn = min(deg[node], CAP);
    const int* brow = bucket + node * CAP;

    if (dn > 0) {
        uint4 A[4], B[4];
        load_batch(brow, 0, dn, node, xlb_b, lane16, A);
        int k = 0;
        while (true) {
            int kB = k + 4;
            bool hasB = kB < dn;
            if (hasB) load_batch(brow, kB, dn, node, xlb_b, lane16, B);
            process_batch(A, dn - k, xr2, a2, sl, acc, m, d);
            if (!hasB) break;
            int kA = k + 8;
            bool hasA = kA < dn;
            if (hasA) load_batch(brow, kA, dn, node, xlb_b, lane16, A);
            process_batch(B, dn - kB, xr2, a2, sl, acc, m, d);
            if (!hasA) break;
            k = kA;
        }
    }

    float inv = 1.f / (d + 1e-16f);
    float4 b0 = *(const float4*)(bias + cbase);
    float4 b1 = *(const float4*)(bias + cbase + 4);
    float bb[8] = {b0.x, b0.y, b0.z, b0.w, b1.x, b1.y, b1.z, b1.w};
    float o[8];
#pragma unroll
    for (int j = 0; j < 8; j++) o[j] = fmaf(acc[j], inv, bb[j]);
    float* op = out + (size_t)node * FDIM + cbase;
    f32x4 ov0 = {o[0], o[1], o[2], o[3]};
    f32x4 ov1 = {o[4], o[5], o[6], o[7]};
    __builtin_nontemporal_store(ov0, (f32x4*)op);        // write-once, keep L2 for xlb
    __builtin_nontemporal_store(ov1, (f32x4*)(op + 4));
}

// ---------------------------------------------------------------------------
extern "C" void kernel_launch(void* const* d_in, const int* in_sizes, int n_in,
                              void* d_out, int out_size, void* d_ws, size_t ws_size,
                              hipStream_t stream) {
    const float* feat = (const float*)d_in[0];
    const int*   ei   = (const int*)d_in[1];
    const float* Wl   = (const float*)d_in[2];
    const float* Wr   = (const float*)d_in[3];
    const float* att  = (const float*)d_in[4];
    const float* bias = (const float*)d_in[5];
    float* out = (float*)d_out;

    char* ws = (char*)d_ws;
    size_t off = 0;
    unsigned int* xlb = (unsigned int*)(ws + off); off += (size_t)N_NODES * 256 * sizeof(unsigned int);
    int* deg    = (int*)(ws + off); off += (size_t)N_NODES * sizeof(int);
    int* bucket = (int*)(ws + off); off += ((size_t)N_NODES * CAP + 16) * sizeof(int);
    (void)ws_size; (void)in_sizes; (void)n_in; (void)out_size;

    hipError_t _e = hipMemsetAsync(deg, 0, (size_t)N_NODES * sizeof(int), stream); (void)_e;
    preproc_kernel<<<GEMM_BLKS + FILL_BLKS, 256, 0, stream>>>(feat, Wl, xlb, ei, deg, bucket);
    gat_aggregate_kernel<<<N_NODES / 4, 256, 0, stream>>>(
        feat, Wl, Wr, att, bias, (const char*)xlb, deg, bucket, out);
}

// Round 9
// 322.190 us; speedup vs baseline: 1.1836x; 1.1836x over previous
//
#include <hip/hip_runtime.h>
#include <math.h>

#define N_NODES 50000
#define N_EDGES 800000
#define FDIM 512                 // HEADS*OUT_CH
#define NEG_SLOPE 0.2f
#define CAP 64                   // bucket slots per node; in-deg ~Poisson(16), max~40

#define GEMM_BLKS 782            // ceil(50000/64)
#define FILL_BLKS 3125           // ceil(800000/256) — 1 edge/thread

typedef _Float16 v2h __attribute__((ext_vector_type(2)));
typedef _Float16 v8h __attribute__((ext_vector_type(8)));
typedef float f32x4 __attribute__((ext_vector_type(4)));

#if __has_builtin(__builtin_amdgcn_exp2f)
#define EXP2(x) __builtin_amdgcn_exp2f(x)
#else
#define EXP2(x) __expf((x) * 0.69314718056f)
#endif
#define LOG2E 1.44269504089f

__device__ __forceinline__ v2h pack_h2(float a, float b) {
    v2h r; r.x = (_Float16)a; r.y = (_Float16)b; return r;
}

// ---------------------------------------------------------------------------
// x_l = feat @ W_l, stored as packed fp16 pairs (separate kernel so rocprof
// reports its duration — diagnostic for the ~150 µs non-aggregate gap).
__global__ __launch_bounds__(256) void gemm_xl_kernel(const float* __restrict__ feat,
                                                      const float* __restrict__ Wl,
                                                      unsigned int* __restrict__ xlb) {
    int t = threadIdx.x;
    __shared__ float fsh[64 * 16];
    int node0 = blockIdx.x * 64;
    int nvalid = min(64, N_NODES - node0);

    float w0[16], w1[16];
#pragma unroll
    for (int k = 0; k < 16; k++) {
        float2 w = ((const float2*)(Wl + k * FDIM))[t];
        w0[k] = w.x; w1[k] = w.y;
    }
    if (t < nvalid * 4) {
        ((float4*)fsh)[t] = ((const float4*)(feat + (size_t)node0 * 16))[t];
    }
    __syncthreads();

    for (int n = 0; n < nvalid; n++) {
        const float4* fq = (const float4*)(fsh + n * 16);
        float4 q0 = fq[0], q1 = fq[1], q2 = fq[2], q3 = fq[3];
        float fr[16] = {q0.x, q0.y, q0.z, q0.w, q1.x, q1.y, q1.z, q1.w,
                        q2.x, q2.y, q2.z, q2.w, q3.x, q3.y, q3.z, q3.w};
        float a0 = 0.f, a1 = 0.f;
#pragma unroll
        for (int k = 0; k < 16; k++) {
            a0 = fmaf(fr[k], w0[k], a0);
            a1 = fmaf(fr[k], w1[k], a1);
        }
        v2h hv = pack_h2(a0, a1);
        xlb[(size_t)(node0 + n) * 256 + t] = __builtin_bit_cast(unsigned int, hv);
    }
}

// Scatter edges into per-dst buckets (1 edge/thread — proven best config).
__global__ __launch_bounds__(256) void fill_bucket_kernel(const int* __restrict__ ei,
                                                          int* __restrict__ deg,
                                                          int* __restrict__ bucket) {
    int t = threadIdx.x;
    bool is64 = true;
#pragma unroll
    for (int i = 0; i < 16; i++) is64 = is64 && (ei[2 * i + 1] == 0);
    int e = blockIdx.x * 256 + t;
    if (e < N_EDGES) {
        int src = is64 ? ei[2 * e] : ei[e];
        int dst = is64 ? ei[2 * (N_EDGES + e)] : ei[N_EDGES + e];
        int pos = atomicAdd(&deg[dst], 1);
        if (pos < CAP) bucket[dst * CAP + pos] = src;
    }
}

// ---------------------------------------------------------------------------
// DPP rotate-add within each 16-lane row (one head): cheap all-reduce.
#define DPP_ROR_ADD(x, ctrl) \
    ((x) + __int_as_float(__builtin_amdgcn_update_dpp(0, __float_as_int(x), (ctrl), 0xF, 0xF, true)))

// Per-lane partial score over 8 fp16 channels; a2 is att*log2e in fp16.
__device__ __forceinline__ float score8(uint4 u, const v2h* __restrict__ xr2,
                                        const v2h* __restrict__ a2, v2h sl) {
    v2h x0 = __builtin_bit_cast(v2h, u.x);
    v2h x1 = __builtin_bit_cast(v2h, u.y);
    v2h x2 = __builtin_bit_cast(v2h, u.z);
    v2h x3 = __builtin_bit_cast(v2h, u.w);
#if __has_builtin(__builtin_amdgcn_fdot2)
    float ps = 0.f;
    v2h s;
    s = x0 + xr2[0]; s = __builtin_elementwise_max(s, s * sl);
    ps = __builtin_amdgcn_fdot2(s, a2[0], ps, false);
    s = x1 + xr2[1]; s = __builtin_elementwise_max(s, s * sl);
    ps = __builtin_amdgcn_fdot2(s, a2[1], ps, false);
    s = x2 + xr2[2]; s = __builtin_elementwise_max(s, s * sl);
    ps = __builtin_amdgcn_fdot2(s, a2[2], ps, false);
    s = x3 + xr2[3]; s = __builtin_elementwise_max(s, s * sl);
    ps = __builtin_amdgcn_fdot2(s, a2[3], ps, false);
    return ps;
#else
    v2h ps = {(_Float16)0.f, (_Float16)0.f};
    v2h s;
    s = x0 + xr2[0]; ps += __builtin_elementwise_max(s, s * sl) * a2[0];
    s = x1 + xr2[1]; ps += __builtin_elementwise_max(s, s * sl) * a2[1];
    s = x2 + xr2[2]; ps += __builtin_elementwise_max(s, s * sl) * a2[2];
    s = x3 + xr2[3]; ps += __builtin_elementwise_max(s, s * sl) * a2[3];
    return (float)ps.x + (float)ps.y;
#endif
}

// Gather one batch of 4 edges; invalid slots re-load the node's own row
// (harmless, L2-hot). 32-bit byte offsets (row = 1 KB, table 51 MB).
__device__ __forceinline__ void load_batch(const int* __restrict__ brow, int k, int dn,
                                           int node, const char* __restrict__ xlb_b,
                                           unsigned lane16, uint4* __restrict__ u) {
    int4 q = *(const int4*)(brow + k);
    unsigned o0 = ((unsigned)((k     < dn) ? q.x : node) << 10) + lane16;
    unsigned o1 = ((unsigned)((k + 1 < dn) ? q.y : node) << 10) + lane16;
    unsigned o2 = ((unsigned)((k + 2 < dn) ? q.z : node) << 10) + lane16;
    unsigned o3 = ((unsigned)((k + 3 < dn) ? q.w : node) << 10) + lane16;
    u[0] = *(const uint4*)(xlb_b + o0);
    u[1] = *(const uint4*)(xlb_b + o1);
    u[2] = *(const uint4*)(xlb_b + o2);
    u[3] = *(const uint4*)(xlb_b + o3);
}

// Single-path online-softmax update (exp2-space); r masks the tail batch.
__device__ __forceinline__ void process_batch(const uint4* __restrict__ u, int r,
                                              const v2h* __restrict__ xr2,
                                              const v2h* __restrict__ a2, v2h sl,
                                              float* __restrict__ acc,
                                              float& m, float& d) {
    float p0 = score8(u[0], xr2, a2, sl);
    float p1 = score8(u[1], xr2, a2, sl);
    float p2 = score8(u[2], xr2, a2, sl);
    float p3 = score8(u[3], xr2, a2, sl);

    // interleaved DPP all-reduce within each 16-lane head group
    p0 = DPP_ROR_ADD(p0, 0x128); p1 = DPP_ROR_ADD(p1, 0x128);
    p2 = DPP_ROR_ADD(p2, 0x128); p3 = DPP_ROR_ADD(p3, 0x128);
    p0 = DPP_ROR_ADD(p0, 0x124); p1 = DPP_ROR_ADD(p1, 0x124);
    p2 = DPP_ROR_ADD(p2, 0x124); p3 = DPP_ROR_ADD(p3, 0x124);
    p0 = DPP_ROR_ADD(p0, 0x122); p1 = DPP_ROR_ADD(p1, 0x122);
    p2 = DPP_ROR_ADD(p2, 0x122); p3 = DPP_ROR_ADD(p3, 0x122);
    p0 = DPP_ROR_ADD(p0, 0x121); p1 = DPP_ROR_ADD(p1, 0x121);
    p2 = DPP_ROR_ADD(p2, 0x121); p3 = DPP_ROR_ADD(p3, 0x121);

    if (r < 2) p1 = -INFINITY;
    if (r < 3) p2 = -INFINITY;
    if (r < 4) p3 = -INFINITY;

    float nm = fmaxf(fmaxf(fmaxf(m, p0), fmaxf(p1, p2)), p3);
    float sc = EXP2(m - nm);
    float w0 = EXP2(p0 - nm);
    float w1 = EXP2(p1 - nm);
    float w2 = EXP2(p2 - nm);
    float w3 = EXP2(p3 - nm);
    d = fmaf(d, sc, (w0 + w1) + (w2 + w3));

    v8h h0 = __builtin_bit_cast(v8h, u[0]);
    v8h h1 = __builtin_bit_cast(v8h, u[1]);
    v8h h2 = __builtin_bit_cast(v8h, u[2]);
    v8h h3 = __builtin_bit_cast(v8h, u[3]);
#pragma unroll
    for (int j = 0; j < 8; j++) {
        float v = acc[j] * sc;
        v = fmaf(w0, (float)h0[j], v);   // v_fma_mix-fusable
        v = fmaf(w1, (float)h1[j], v);
        v = fmaf(w2, (float)h2[j], v);
        v = fmaf(w3, (float)h3[j], v);
        acc[j] = v;
    }
    m = nm;
}

// One wave per destination node, 4 waves per block. Self-loop row LOADED from
// the xlb table (bit-exact, 16 B/lane, L2-hot — NOT recomputed: R8 proved the
// in-register Wl recompute costs 32 KB/wave of weight reads, -70 µs). Edge
// loop then runs over dn real edges only.
__global__ __launch_bounds__(256) void gat_aggregate_kernel(
        const float* __restrict__ feat, const float* __restrict__ Wr,
        const float* __restrict__ att,  const float* __restrict__ bias,
        const char* __restrict__ xlb_b, const int* __restrict__ deg,
        const int* __restrict__ bucket, float* __restrict__ out) {
    int t = threadIdx.x;
    int wave = t >> 6, lane = t & 63;
    int node = blockIdx.x * 4 + wave;    // grid*4 == N_NODES exactly
    int cbase = lane * 8;
    unsigned lane16 = (unsigned)lane << 4;

    // feat[node] broadcast
    float f[16];
    {
        const float4* fp = (const float4*)(feat + (size_t)node * 16);
        float4 f0 = fp[0], f1 = fp[1], f2 = fp[2], f3 = fp[3];
        f[0]=f0.x; f[1]=f0.y; f[2]=f0.z; f[3]=f0.w;
        f[4]=f1.x; f[5]=f1.y; f[6]=f1.z; f[7]=f1.w;
        f[8]=f2.x; f[9]=f2.y; f[10]=f2.z; f[11]=f2.w;
        f[12]=f3.x; f[13]=f3.y; f[14]=f3.z; f[15]=f3.w;
    }

    // x_r[node] for this lane's 8 channels, fp32 accumulate then pack to fp16
    float xr[8];
#pragma unroll
    for (int j = 0; j < 8; j++) xr[j] = 0.f;
#pragma unroll
    for (int k = 0; k < 16; k++) {
        float fk = f[k];
        float4 wa = *(const float4*)(Wr + k * FDIM + cbase);
        float4 wb = *(const float4*)(Wr + k * FDIM + cbase + 4);
        xr[0] = fmaf(fk, wa.x, xr[0]); xr[1] = fmaf(fk, wa.y, xr[1]);
        xr[2] = fmaf(fk, wa.z, xr[2]); xr[3] = fmaf(fk, wa.w, xr[3]);
        xr[4] = fmaf(fk, wb.x, xr[4]); xr[5] = fmaf(fk, wb.y, xr[5]);
        xr[6] = fmaf(fk, wb.z, xr[6]); xr[7] = fmaf(fk, wb.w, xr[7]);
    }
    v2h xr2[4];
    xr2[0] = pack_h2(xr[0], xr[1]);
    xr2[1] = pack_h2(xr[2], xr[3]);
    xr2[2] = pack_h2(xr[4], xr[5]);
    xr2[3] = pack_h2(xr[6], xr[7]);

    // att * log2e, packed fp16 (single rounding)
    v2h a2[4];
    {
        float4 a0 = *(const float4*)(att + cbase);
        float4 a1 = *(const float4*)(att + cbase + 4);
        a2[0] = pack_h2(a0.x * LOG2E, a0.y * LOG2E);
        a2[1] = pack_h2(a0.z * LOG2E, a0.w * LOG2E);
        a2[2] = pack_h2(a1.x * LOG2E, a1.y * LOG2E);
        a2[3] = pack_h2(a1.z * LOG2E, a1.w * LOG2E);
    }
    const v2h sl = {(_Float16)NEG_SLOPE, (_Float16)NEG_SLOPE};

    // Self edge from the table (bit-exact with gathered rows).
    uint4 su = *(const uint4*)(xlb_b + ((unsigned)node << 10) + lane16);
    float p_self = score8(su, xr2, a2, sl);
    p_self = DPP_ROR_ADD(p_self, 0x128);
    p_self = DPP_ROR_ADD(p_self, 0x124);
    p_self = DPP_ROR_ADD(p_self, 0x122);
    p_self = DPP_ROR_ADD(p_self, 0x121);
    float m = p_self, d = 1.f;
    float acc[8];
    {
        v8h sh = __builtin_bit_cast(v8h, su);
#pragma unroll
        for (int j = 0; j < 8; j++) acc[j] = (float)sh[j];
    }

    int dn = min(deg[node], CAP);
    const int* brow = bucket + node * CAP;

    if (dn > 0) {
        uint4 A[4], B[4];
        load_batch(brow, 0, dn, node, xlb_b, lane16, A);
        int k = 0;
        while (true) {
            int kB = k + 4;
            bool hasB = kB < dn;
            if (hasB) load_batch(brow, kB, dn, node, xlb_b, lane16, B);
            process_batch(A, dn - k, xr2, a2, sl, acc, m, d);
            if (!hasB) break;
            int kA = k + 8;
            bool hasA = kA < dn;
            if (hasA) load_batch(brow, kA, dn, node, xlb_b, lane16, A);
            process_batch(B, dn - kB, xr2, a2, sl, acc, m, d);
            if (!hasA) break;
            k = kA;
        }
    }

    float inv = 1.f / (d + 1e-16f);
    float4 b0 = *(const float4*)(bias + cbase);
    float4 b1 = *(const float4*)(bias + cbase + 4);
    float bb[8] = {b0.x, b0.y, b0.z, b0.w, b1.x, b1.y, b1.z, b1.w};
    float o[8];
#pragma unroll
    for (int j = 0; j < 8; j++) o[j] = fmaf(acc[j], inv, bb[j]);
    float* op = out + (size_t)node * FDIM + cbase;
    f32x4 ov0 = {o[0], o[1], o[2], o[3]};
    f32x4 ov1 = {o[4], o[5], o[6], o[7]};
    __builtin_nontemporal_store(ov0, (f32x4*)op);        // write-once, keep L2 for xlb
    __builtin_nontemporal_store(ov1, (f32x4*)(op + 4));
}

// ---------------------------------------------------------------------------
extern "C" void kernel_launch(void* const* d_in, const int* in_sizes, int n_in,
                              void* d_out, int out_size, void* d_ws, size_t ws_size,
                              hipStream_t stream) {
    const float* feat = (const float*)d_in[0];
    const int*   ei   = (const int*)d_in[1];
    const float* Wl   = (const float*)d_in[2];
    const float* Wr   = (const float*)d_in[3];
    const float* att  = (const float*)d_in[4];
    const float* bias = (const float*)d_in[5];
    float* out = (float*)d_out;

    char* ws = (char*)d_ws;
    size_t off = 0;
    unsigned int* xlb = (unsigned int*)(ws + off); off += (size_t)N_NODES * 256 * sizeof(unsigned int);
    int* deg    = (int*)(ws + off); off += (size_t)N_NODES * sizeof(int);
    int* bucket = (int*)(ws + off); off += ((size_t)N_NODES * CAP + 16) * sizeof(int);
    (void)ws_size; (void)in_sizes; (void)n_in; (void)out_size;

    hipError_t _e = hipMemsetAsync(deg, 0, (size_t)N_NODES * sizeof(int), stream); (void)_e;
    gemm_xl_kernel<<<GEMM_BLKS, 256, 0, stream>>>(feat, Wl, xlb);
    fill_bucket_kernel<<<FILL_BLKS, 256, 0, stream>>>(ei, deg, bucket);
    gat_aggregate_kernel<<<N_NODES / 4, 256, 0, stream>>>(
        feat, Wr, att, bias, (const char*)xlb, deg, bucket, out);
}